// Round 1
// baseline (503.283 us; speedup 1.0000x reference)
//
#include <hip/hip_runtime.h>

// Problem constants
#define BB 16
#define CC 128
#define MM 32
#define NN 16384   // H*W = 128*128

// Workspace layout (float offsets)
#define WS_KV    0        // [16][32][32] = 16384
#define WS_KS    16384    // [16][32]     = 512
#define WS_YSUM  16896    // [128]
#define WS_YSQ   17024    // [128]
#define WS_SCALE 17152    // [128]
#define WS_BIAS  17280    // [128]
#define WS_W2    17408    // [16][128][32] = 65536
#define WS_WQT   82944    // [128][32]
#define WS_WKT   87040    // [128][32]
#define WS_WVT   91136    // [128][32]
// total = 95232 floats = 380928 bytes

__device__ __forceinline__ float phi_f(float z) {
    // elu(z) + 1  (alpha = 1):  z>0 -> z+1 ; z<=0 -> exp(z)
    return z > 0.f ? z + 1.f : __expf(z);
}

// ---------------------------------------------------------------------------
// Transpose the three projection weights [32][128] -> [128][32] so the hot
// loops read 32 contiguous floats per channel (uniform address -> s_load).
__global__ void wt_kernel(const float* __restrict__ Wq, const float* __restrict__ Wk,
                          const float* __restrict__ Wv, float* __restrict__ ws) {
    const int c = threadIdx.x;  // 128 threads
    float* wqT = ws + WS_WQT;
    float* wkT = ws + WS_WKT;
    float* wvT = ws + WS_WVT;
    #pragma unroll
    for (int m = 0; m < MM; ++m) {
        wqT[c * MM + m] = Wq[m * CC + c];
        wkT[c * MM + m] = Wk[m * CC + c];
        wvT[c * MM + m] = Wv[m * CC + c];
    }
}

// ---------------------------------------------------------------------------
// Pass 1: K = phi(Wk x), V = Wv x per pixel; accumulate KV[b][m][v], Ks[b][m].
// grid (32, 16) blocks of 256; each block: 512 pixels in 2 tiles of 256.
__global__ __launch_bounds__(256) void pass1_kernel(const float* __restrict__ x,
                                                    float* ws) {
    __shared__ __align__(16) float kt[256 * 36];
    __shared__ __align__(16) float vt[256 * 36];

    const float* wkT = ws + WS_WKT;
    const float* wvT = ws + WS_WVT;
    float* kv_g = ws + WS_KV;
    float* ks_g = ws + WS_KS;

    const int b = blockIdx.y;
    const int t = threadIdx.x;
    const int l = t & 63;
    const int g = t >> 6;             // wave id: handles pixel range [64g, 64g+64)
    const int m0 = (l >> 3) << 2;     // K row group (0,4,...,28)
    const int v0 = (l & 7) << 2;      // V col group (0,4,...,28)

    float kvacc[16];
    #pragma unroll
    for (int i = 0; i < 16; ++i) kvacc[i] = 0.f;
    float ksacc[4] = {0.f, 0.f, 0.f, 0.f};

    for (int tile = 0; tile < 2; ++tile) {
        const int n = (blockIdx.x << 9) + (tile << 8) + t;

        // ---- phase A: this thread's pixel -> K[32], V[32] in registers
        float ka[32], va[32];
        #pragma unroll
        for (int m = 0; m < 32; ++m) { ka[m] = 0.f; va[m] = 0.f; }
        const float* xp = x + (size_t)b * CC * NN + n;
        #pragma unroll 8
        for (int c = 0; c < CC; ++c) {
            const float xv = xp[(size_t)c * NN];
            const float4* wk4 = (const float4*)(wkT + (c << 5));
            const float4* wv4 = (const float4*)(wvT + (c << 5));
            #pragma unroll
            for (int q = 0; q < 8; ++q) {
                const float4 wa = wk4[q];
                const float4 wb = wv4[q];
                ka[4*q+0] = fmaf(wa.x, xv, ka[4*q+0]);
                ka[4*q+1] = fmaf(wa.y, xv, ka[4*q+1]);
                ka[4*q+2] = fmaf(wa.z, xv, ka[4*q+2]);
                ka[4*q+3] = fmaf(wa.w, xv, ka[4*q+3]);
                va[4*q+0] = fmaf(wb.x, xv, va[4*q+0]);
                va[4*q+1] = fmaf(wb.y, xv, va[4*q+1]);
                va[4*q+2] = fmaf(wb.z, xv, va[4*q+2]);
                va[4*q+3] = fmaf(wb.w, xv, va[4*q+3]);
            }
        }

        __syncthreads();   // previous tile's phase B done before overwrite
        #pragma unroll
        for (int q = 0; q < 8; ++q) {
            float4 kk;
            kk.x = phi_f(ka[4*q+0]); kk.y = phi_f(ka[4*q+1]);
            kk.z = phi_f(ka[4*q+2]); kk.w = phi_f(ka[4*q+3]);
            *(float4*)&kt[t * 36 + 4*q] = kk;
            float4 vv;
            vv.x = va[4*q+0]; vv.y = va[4*q+1]; vv.z = va[4*q+2]; vv.w = va[4*q+3];
            *(float4*)&vt[t * 36 + 4*q] = vv;
        }
        __syncthreads();

        // ---- phase B: rank-64 update of this thread's 4x4 KV subtile
        const int pbase = g << 6;
        for (int pp = 0; pp < 64; ++pp) {
            const int p = pbase + pp;
            const float4 kf = *(const float4*)&kt[p * 36 + m0];
            const float4 vf = *(const float4*)&vt[p * 36 + v0];
            kvacc[ 0] = fmaf(kf.x, vf.x, kvacc[ 0]);
            kvacc[ 1] = fmaf(kf.x, vf.y, kvacc[ 1]);
            kvacc[ 2] = fmaf(kf.x, vf.z, kvacc[ 2]);
            kvacc[ 3] = fmaf(kf.x, vf.w, kvacc[ 3]);
            kvacc[ 4] = fmaf(kf.y, vf.x, kvacc[ 4]);
            kvacc[ 5] = fmaf(kf.y, vf.y, kvacc[ 5]);
            kvacc[ 6] = fmaf(kf.y, vf.z, kvacc[ 6]);
            kvacc[ 7] = fmaf(kf.y, vf.w, kvacc[ 7]);
            kvacc[ 8] = fmaf(kf.z, vf.x, kvacc[ 8]);
            kvacc[ 9] = fmaf(kf.z, vf.y, kvacc[ 9]);
            kvacc[10] = fmaf(kf.z, vf.z, kvacc[10]);
            kvacc[11] = fmaf(kf.z, vf.w, kvacc[11]);
            kvacc[12] = fmaf(kf.w, vf.x, kvacc[12]);
            kvacc[13] = fmaf(kf.w, vf.y, kvacc[13]);
            kvacc[14] = fmaf(kf.w, vf.z, kvacc[14]);
            kvacc[15] = fmaf(kf.w, vf.w, kvacc[15]);
            if (v0 == 0) {
                ksacc[0] += kf.x; ksacc[1] += kf.y;
                ksacc[2] += kf.z; ksacc[3] += kf.w;
            }
        }
    }

    float* kvb = kv_g + (b << 10);
    #pragma unroll
    for (int i = 0; i < 4; ++i)
        #pragma unroll
        for (int j = 0; j < 4; ++j)
            atomicAdd(&kvb[(m0 + i) * 32 + (v0 + j)], kvacc[i * 4 + j]);
    if (v0 == 0) {
        #pragma unroll
        for (int i = 0; i < 4; ++i)
            atomicAdd(&ks_g[(b << 5) + m0 + i], ksacc[i]);
    }
}

// ---------------------------------------------------------------------------
// W2[b] = Wout (128x32) @ KV[b] (32x32)
__global__ __launch_bounds__(256) void w2_kernel(const float* __restrict__ Wout,
                                                 float* ws) {
    const int b = blockIdx.x;
    const float* kvb = ws + WS_KV + (b << 10);
    float* w2b = ws + WS_W2 + (b << 12);
    const int t = threadIdx.x;
    #pragma unroll
    for (int i = 0; i < 16; ++i) {
        const int o = (i << 8) + t;       // o = c*32 + v
        const int c = o >> 5, v = o & 31;
        float acc = 0.f;
        #pragma unroll
        for (int m = 0; m < 32; ++m)
            acc = fmaf(Wout[(c << 5) + m], kvb[(m << 5) + v], acc);
        w2b[o] = acc;
    }
}

// ---------------------------------------------------------------------------
// Pass 2: Q = phi(Wq x); denom; y[c,n] = sum_v W2[c,v] * Q[v,n] * inv -> d_out
// grid (64, 16) blocks of 256, one pixel per thread.
__global__ __launch_bounds__(256) void pass2_kernel(const float* __restrict__ x,
                                                    const float* ws,
                                                    float* __restrict__ out) {
    const float* wqT = ws + WS_WQT;
    const int b = blockIdx.y;
    const float* ksb = ws + WS_KS + (b << 5);
    const float* w2b = ws + WS_W2 + (b << 12);
    const int n = (blockIdx.x << 8) + threadIdx.x;

    float qa[32];
    #pragma unroll
    for (int m = 0; m < 32; ++m) qa[m] = 0.f;

    const float* xp = x + (size_t)b * CC * NN + n;
    #pragma unroll 8
    for (int c = 0; c < CC; ++c) {
        const float xv = xp[(size_t)c * NN];
        const float4* wq4 = (const float4*)(wqT + (c << 5));
        #pragma unroll
        for (int q = 0; q < 8; ++q) {
            const float4 w = wq4[q];
            qa[4*q+0] = fmaf(w.x, xv, qa[4*q+0]);
            qa[4*q+1] = fmaf(w.y, xv, qa[4*q+1]);
            qa[4*q+2] = fmaf(w.z, xv, qa[4*q+2]);
            qa[4*q+3] = fmaf(w.w, xv, qa[4*q+3]);
        }
    }
    #pragma unroll
    for (int m = 0; m < 32; ++m) qa[m] = phi_f(qa[m]);

    float denom = 1e-6f;
    #pragma unroll
    for (int m = 0; m < 32; ++m) denom = fmaf(qa[m], ksb[m], denom);
    const float inv = 1.0f / (16384.0f * denom);
    #pragma unroll
    for (int m = 0; m < 32; ++m) qa[m] *= inv;   // fold 1/(n*denom) into Q

    float* op = out + (size_t)b * CC * NN + n;
    #pragma unroll 2
    for (int c = 0; c < CC; ++c) {
        const float4* w4 = (const float4*)(w2b + (c << 5));
        float t0 = 0.f, t1 = 0.f, t2 = 0.f, t3 = 0.f;
        #pragma unroll
        for (int q = 0; q < 8; ++q) {
            const float4 w = w4[q];
            t0 = fmaf(w.x, qa[4*q+0], t0);
            t1 = fmaf(w.y, qa[4*q+1], t1);
            t2 = fmaf(w.z, qa[4*q+2], t2);
            t3 = fmaf(w.w, qa[4*q+3], t3);
        }
        op[(size_t)c * NN] = (t0 + t1) + (t2 + t3);
    }
}

// ---------------------------------------------------------------------------
// Per-channel sums of y and y^2 over (B, N).  grid (8, 128, 16), 256 threads.
__global__ __launch_bounds__(256) void stats_kernel(const float* __restrict__ y,
                                                    float* ws) {
    float* ysum = ws + WS_YSUM;
    float* ysq  = ws + WS_YSQ;
    const int c = blockIdx.y;
    const float* p = y + ((size_t)blockIdx.z * CC + c) * NN + (blockIdx.x << 11) + threadIdx.x;
    float s = 0.f, s2 = 0.f;
    #pragma unroll
    for (int i = 0; i < 8; ++i) {
        const float v = p[i << 8];
        s += v;
        s2 = fmaf(v, v, s2);
    }
    #pragma unroll
    for (int d = 1; d < 64; d <<= 1) {
        s  += __shfl_xor(s, d);
        s2 += __shfl_xor(s2, d);
    }
    if ((threadIdx.x & 63) == 0) {
        atomicAdd(&ysum[c], s);
        atomicAdd(&ysq[c], s2);
    }
}

// ---------------------------------------------------------------------------
__global__ void finalize_kernel(const float* __restrict__ gamma,
                                const float* __restrict__ beta, float* ws) {
    const int c = threadIdx.x;  // 128 threads
    const float invBN = 1.0f / 262144.0f;  // 1/(B*N)
    const float mean = ws[WS_YSUM + c] * invBN;
    const float var  = ws[WS_YSQ + c] * invBN - mean * mean;
    const float s = gamma[c] * rsqrtf(var + 1e-5f);
    ws[WS_SCALE + c] = s;
    ws[WS_BIAS + c]  = fmaf(-mean, s, beta[c]);
}

// ---------------------------------------------------------------------------
// In-place BN normalize of d_out.  float4 grid-stride.
__global__ __launch_bounds__(256) void norm_kernel(float* __restrict__ y,
                                                   const float* ws) {
    const float* scale = ws + WS_SCALE;
    const float* bias  = ws + WS_BIAS;
    float4* y4 = (float4*)y;
    const int total = (BB * CC * NN) / 4;  // 8388608
    for (int idx = blockIdx.x * 256 + threadIdx.x; idx < total;
         idx += gridDim.x * 256) {
        float4 v = y4[idx];
        const int c = (idx >> 12) & 127;   // 4096 float4 per (b,c) row
        const float s = scale[c], tt = bias[c];
        v.x = fmaf(v.x, s, tt);
        v.y = fmaf(v.y, s, tt);
        v.z = fmaf(v.z, s, tt);
        v.w = fmaf(v.w, s, tt);
        y4[idx] = v;
    }
}

// ---------------------------------------------------------------------------
extern "C" void kernel_launch(void* const* d_in, const int* in_sizes, int n_in,
                              void* d_out, int out_size, void* d_ws, size_t ws_size,
                              hipStream_t stream) {
    const float* x     = (const float*)d_in[0];
    const float* Wq    = (const float*)d_in[1];
    const float* Wk    = (const float*)d_in[2];
    const float* Wv    = (const float*)d_in[3];
    const float* Wout  = (const float*)d_in[4];
    const float* gamma = (const float*)d_in[5];
    const float* beta  = (const float*)d_in[6];
    float* ws  = (float*)d_ws;
    float* out = (float*)d_out;

    // zero the accumulators (kv, ks, ysum, ysq) every launch
    hipMemsetAsync(ws, 0, (size_t)WS_SCALE * sizeof(float), stream);

    wt_kernel<<<1, 128, 0, stream>>>(Wq, Wk, Wv, ws);
    pass1_kernel<<<dim3(32, 16), 256, 0, stream>>>(x, ws);
    w2_kernel<<<16, 256, 0, stream>>>(Wout, ws);
    pass2_kernel<<<dim3(64, 16), 256, 0, stream>>>(x, ws, out);
    stats_kernel<<<dim3(8, 128, 16), 256, 0, stream>>>(out, ws);
    finalize_kernel<<<1, 128, 0, stream>>>(gamma, beta, ws);
    norm_kernel<<<2048, 256, 0, stream>>>(out, ws);
}

// Round 2
// 310.536 us; speedup vs baseline: 1.6207x; 1.6207x over previous
//
#include <hip/hip_runtime.h>

// Problem constants
#define BB 16
#define CC 128
#define MM 32
#define NN 16384   // H*W

// Workspace layout (float offsets)
#define WS_KV     0        // [16][32][32]
#define WS_KS     16384    // [16][32]
#define WS_SQ     16896    // [16][32]   sum_n Q'
#define WS_QQ     17408    // [16][32][32] sum_n Q'Q'^T
#define WS_YSUM   33792    // [128]
#define WS_YSQ    33920    // [128]
#define WS_ACCEND 34048    // zeroed region end
#define WS_SCALE  34048    // [128]
#define WS_BIAS   34176    // [128]
#define WS_W2     34304    // [16][128][32]
#define WS_WQT    99840    // [128][32]
#define WS_WKT    103936   // [128][32]
#define WS_WVT    108032   // [128][32]
// total = 112128 floats = 448 KB

__device__ __forceinline__ float phi_f(float z) {
    // elu(z) + 1 (alpha=1): z>0 -> z+1 ; z<=0 -> exp(z)
    return z > 0.f ? z + 1.f : __expf(z);
}

// ---------------------------------------------------------------------------
// Transpose projection weights [32][128] -> [128][32] for contiguous rows.
__global__ void wt_kernel(const float* __restrict__ Wq, const float* __restrict__ Wk,
                          const float* __restrict__ Wv, float* __restrict__ ws) {
    const int c = threadIdx.x;  // 128
    #pragma unroll
    for (int m = 0; m < MM; ++m) {
        ws[WS_WQT + c * MM + m] = Wq[m * CC + c];
        ws[WS_WKT + c * MM + m] = Wk[m * CC + c];
        ws[WS_WVT + c * MM + m] = Wv[m * CC + c];
    }
}

// ---------------------------------------------------------------------------
// Pass A: single read of x. Per pixel compute k,v,q projections; phi(k), phi(q).
// Store phi(q) into d_out stripes [b][m<32][n]; accumulate KV[b], Ks[b].
// grid (32,16) x 256; 2 tiles of 256 pixels per block.
__global__ __launch_bounds__(256) void proj_kernel(const float* __restrict__ x,
                                                   float* ws, float* __restrict__ qout) {
    __shared__ __align__(16) float kt[256 * 36];
    __shared__ __align__(16) float vt[256 * 36];

    const float* wqT = ws + WS_WQT;
    const float* wkT = ws + WS_WKT;
    const float* wvT = ws + WS_WVT;

    const int b = blockIdx.y;
    const int t = threadIdx.x;
    const int l = t & 63;
    const int g = t >> 6;             // wave id
    const int m0 = (l >> 3) << 2;     // K-row group
    const int v0 = (l & 7) << 2;      // V-col group

    float kvacc[16];
    #pragma unroll
    for (int i = 0; i < 16; ++i) kvacc[i] = 0.f;
    float ksacc[4] = {0.f, 0.f, 0.f, 0.f};

    for (int tile = 0; tile < 2; ++tile) {
        const int n = (blockIdx.x << 9) + (tile << 8) + t;

        float ka[32], va[32], qa[32];
        #pragma unroll
        for (int m = 0; m < 32; ++m) { ka[m] = 0.f; va[m] = 0.f; qa[m] = 0.f; }

        const float* xp = x + (size_t)b * CC * NN + n;
        #pragma unroll 4
        for (int c = 0; c < CC; ++c) {
            const float xv = xp[(size_t)c * NN];
            const float4* wk4 = (const float4*)(wkT + (c << 5));
            const float4* wv4 = (const float4*)(wvT + (c << 5));
            const float4* wq4 = (const float4*)(wqT + (c << 5));
            #pragma unroll
            for (int q = 0; q < 8; ++q) {
                const float4 wa = wk4[q];
                ka[4*q+0] = fmaf(wa.x, xv, ka[4*q+0]);
                ka[4*q+1] = fmaf(wa.y, xv, ka[4*q+1]);
                ka[4*q+2] = fmaf(wa.z, xv, ka[4*q+2]);
                ka[4*q+3] = fmaf(wa.w, xv, ka[4*q+3]);
                const float4 wb = wv4[q];
                va[4*q+0] = fmaf(wb.x, xv, va[4*q+0]);
                va[4*q+1] = fmaf(wb.y, xv, va[4*q+1]);
                va[4*q+2] = fmaf(wb.z, xv, va[4*q+2]);
                va[4*q+3] = fmaf(wb.w, xv, va[4*q+3]);
                const float4 wc = wq4[q];
                qa[4*q+0] = fmaf(wc.x, xv, qa[4*q+0]);
                qa[4*q+1] = fmaf(wc.y, xv, qa[4*q+1]);
                qa[4*q+2] = fmaf(wc.z, xv, qa[4*q+2]);
                qa[4*q+3] = fmaf(wc.w, xv, qa[4*q+3]);
            }
        }

        // store phi(Q) into d_out stripes (channels 0..31 of batch b)
        float* qp = qout + (size_t)b * CC * NN + n;
        #pragma unroll
        for (int m = 0; m < 32; ++m) qp[(size_t)m * NN] = phi_f(qa[m]);

        __syncthreads();   // previous tile's phase-B reads done
        #pragma unroll
        for (int q = 0; q < 8; ++q) {
            float4 kk;
            kk.x = phi_f(ka[4*q+0]); kk.y = phi_f(ka[4*q+1]);
            kk.z = phi_f(ka[4*q+2]); kk.w = phi_f(ka[4*q+3]);
            *(float4*)&kt[t * 36 + 4*q] = kk;
            float4 vv;
            vv.x = va[4*q+0]; vv.y = va[4*q+1]; vv.z = va[4*q+2]; vv.w = va[4*q+3];
            *(float4*)&vt[t * 36 + 4*q] = vv;
        }
        __syncthreads();

        // rank-64 update of this thread's 4x4 KV subtile
        const int pbase = g << 6;
        for (int pp = 0; pp < 64; ++pp) {
            const int p = pbase + pp;
            const float4 kf = *(const float4*)&kt[p * 36 + m0];
            const float4 vf = *(const float4*)&vt[p * 36 + v0];
            kvacc[ 0] = fmaf(kf.x, vf.x, kvacc[ 0]);
            kvacc[ 1] = fmaf(kf.x, vf.y, kvacc[ 1]);
            kvacc[ 2] = fmaf(kf.x, vf.z, kvacc[ 2]);
            kvacc[ 3] = fmaf(kf.x, vf.w, kvacc[ 3]);
            kvacc[ 4] = fmaf(kf.y, vf.x, kvacc[ 4]);
            kvacc[ 5] = fmaf(kf.y, vf.y, kvacc[ 5]);
            kvacc[ 6] = fmaf(kf.y, vf.z, kvacc[ 6]);
            kvacc[ 7] = fmaf(kf.y, vf.w, kvacc[ 7]);
            kvacc[ 8] = fmaf(kf.z, vf.x, kvacc[ 8]);
            kvacc[ 9] = fmaf(kf.z, vf.y, kvacc[ 9]);
            kvacc[10] = fmaf(kf.z, vf.z, kvacc[10]);
            kvacc[11] = fmaf(kf.z, vf.w, kvacc[11]);
            kvacc[12] = fmaf(kf.w, vf.x, kvacc[12]);
            kvacc[13] = fmaf(kf.w, vf.y, kvacc[13]);
            kvacc[14] = fmaf(kf.w, vf.z, kvacc[14]);
            kvacc[15] = fmaf(kf.w, vf.w, kvacc[15]);
            if (v0 == 0) {
                ksacc[0] += kf.x; ksacc[1] += kf.y;
                ksacc[2] += kf.z; ksacc[3] += kf.w;
            }
        }
    }

    // cross-wave LDS reduction, then one atomic per subtile entry per block
    __syncthreads();
    #pragma unroll
    for (int i = 0; i < 16; ++i) kt[t * 17 + i] = kvacc[i];   // stride 17: no bank conflict
    if (v0 == 0) {
        const int r = l >> 3;
        #pragma unroll
        for (int i = 0; i < 4; ++i) vt[(g * 8 + r) * 4 + i] = ksacc[i];
    }
    __syncthreads();
    if (t < 64) {
        float* kvb = ws + WS_KV + (b << 10);
        #pragma unroll
        for (int i = 0; i < 16; ++i) {
            const float s = kt[t*17+i] + kt[(t+64)*17+i] + kt[(t+128)*17+i] + kt[(t+192)*17+i];
            atomicAdd(&kvb[(m0 + (i >> 2)) * 32 + v0 + (i & 3)], s);
        }
    }
    if (t < 8) {
        #pragma unroll
        for (int i = 0; i < 4; ++i) {
            const float s = vt[t*4+i] + vt[(8+t)*4+i] + vt[(16+t)*4+i] + vt[(24+t)*4+i];
            atomicAdd(&ws[WS_KS + (b << 5) + t * 4 + i], s);
        }
    }
}

// ---------------------------------------------------------------------------
// W2[b] = Wout (128x32) @ KV[b] (32x32)
__global__ __launch_bounds__(256) void w2_kernel(const float* __restrict__ Wout,
                                                 float* ws) {
    const int b = blockIdx.x;
    const float* kvb = ws + WS_KV + (b << 10);
    float* w2b = ws + WS_W2 + (b << 12);
    const int t = threadIdx.x;
    #pragma unroll
    for (int i = 0; i < 16; ++i) {
        const int o = (i << 8) + t;
        const int c = o >> 5, v = o & 31;
        float acc = 0.f;
        #pragma unroll
        for (int m = 0; m < 32; ++m)
            acc = fmaf(Wout[(c << 5) + m], kvb[(m << 5) + v], acc);
        w2b[o] = acc;
    }
}

// ---------------------------------------------------------------------------
// Pass C: read phi(Q), fold inv = 1/(n*denom); accumulate Sq[b]=sum Q',
// QQ[b]=sum Q'Q'^T.  grid (16,16) x 256, 4 tiles of 256.
__global__ __launch_bounds__(256) void qq_kernel(const float* qsrc, float* ws) {
    __shared__ __align__(16) float qt[256 * 36];

    const int b = blockIdx.y;
    const int t = threadIdx.x;
    const int l = t & 63;
    const int g = t >> 6;
    const int m0 = (l >> 3) << 2;
    const int v0 = (l & 7) << 2;

    float qqacc[16];
    #pragma unroll
    for (int i = 0; i < 16; ++i) qqacc[i] = 0.f;
    float sqacc[4] = {0.f, 0.f, 0.f, 0.f};

    const float* ksb = ws + WS_KS + (b << 5);

    for (int tile = 0; tile < 4; ++tile) {
        const int n = (blockIdx.x << 10) + (tile << 8) + t;
        const float* qp = qsrc + (size_t)b * CC * NN + n;
        float qa[32];
        #pragma unroll
        for (int m = 0; m < 32; ++m) qa[m] = qp[(size_t)m * NN];

        float denom = 1e-6f;
        #pragma unroll
        for (int m = 0; m < 32; ++m) denom = fmaf(qa[m], ksb[m], denom);
        const float inv = 1.0f / (16384.0f * denom);
        #pragma unroll
        for (int m = 0; m < 32; ++m) qa[m] *= inv;

        __syncthreads();
        #pragma unroll
        for (int q = 0; q < 8; ++q)
            *(float4*)&qt[t * 36 + 4*q] = *(float4*)&qa[4*q];
        __syncthreads();

        const int pbase = g << 6;
        for (int pp = 0; pp < 64; ++pp) {
            const int p = pbase + pp;
            const float4 uf = *(const float4*)&qt[p * 36 + m0];
            const float4 vf = *(const float4*)&qt[p * 36 + v0];
            qqacc[ 0] = fmaf(uf.x, vf.x, qqacc[ 0]);
            qqacc[ 1] = fmaf(uf.x, vf.y, qqacc[ 1]);
            qqacc[ 2] = fmaf(uf.x, vf.z, qqacc[ 2]);
            qqacc[ 3] = fmaf(uf.x, vf.w, qqacc[ 3]);
            qqacc[ 4] = fmaf(uf.y, vf.x, qqacc[ 4]);
            qqacc[ 5] = fmaf(uf.y, vf.y, qqacc[ 5]);
            qqacc[ 6] = fmaf(uf.y, vf.z, qqacc[ 6]);
            qqacc[ 7] = fmaf(uf.y, vf.w, qqacc[ 7]);
            qqacc[ 8] = fmaf(uf.z, vf.x, qqacc[ 8]);
            qqacc[ 9] = fmaf(uf.z, vf.y, qqacc[ 9]);
            qqacc[10] = fmaf(uf.z, vf.z, qqacc[10]);
            qqacc[11] = fmaf(uf.z, vf.w, qqacc[11]);
            qqacc[12] = fmaf(uf.w, vf.x, qqacc[12]);
            qqacc[13] = fmaf(uf.w, vf.y, qqacc[13]);
            qqacc[14] = fmaf(uf.w, vf.z, qqacc[14]);
            qqacc[15] = fmaf(uf.w, vf.w, qqacc[15]);
            if (v0 == 0) {
                sqacc[0] += uf.x; sqacc[1] += uf.y;
                sqacc[2] += uf.z; sqacc[3] += uf.w;
            }
        }
    }

    __syncthreads();
    #pragma unroll
    for (int i = 0; i < 16; ++i) qt[t * 17 + i] = qqacc[i];
    if (v0 == 0) {
        const int r = l >> 3;
        #pragma unroll
        for (int i = 0; i < 4; ++i) qt[4352 + (g * 8 + r) * 4 + i] = sqacc[i];
    }
    __syncthreads();
    if (t < 64) {
        float* qqb = ws + WS_QQ + (b << 10);
        #pragma unroll
        for (int i = 0; i < 16; ++i) {
            const float s = qt[t*17+i] + qt[(t+64)*17+i] + qt[(t+128)*17+i] + qt[(t+192)*17+i];
            atomicAdd(&qqb[(m0 + (i >> 2)) * 32 + v0 + (i & 3)], s);
        }
    }
    if (t < 8) {
        #pragma unroll
        for (int i = 0; i < 4; ++i) {
            const float s = qt[4352 + t*4+i] + qt[4352 + (8+t)*4+i]
                          + qt[4352 + (16+t)*4+i] + qt[4352 + (24+t)*4+i];
            atomicAdd(&ws[WS_SQ + (b << 5) + t * 4 + i], s);
        }
    }
}

// ---------------------------------------------------------------------------
// BN stats from moments: ysum_c += w2b[c]·Sq_b ; ysq_c += w2b[c]·QQ_b·w2b[c]^T
__global__ __launch_bounds__(128) void bnstat_kernel(float* ws) {
    const int b = blockIdx.x;   // 16
    const int c = threadIdx.x;  // 128
    const float* w2c = ws + WS_W2 + (b << 12) + (c << 5);
    const float* sq  = ws + WS_SQ + (b << 5);
    const float* qq  = ws + WS_QQ + (b << 10);
    float w[32];
    #pragma unroll
    for (int v = 0; v < 32; ++v) w[v] = w2c[v];
    float mb = 0.f;
    #pragma unroll
    for (int v = 0; v < 32; ++v) mb = fmaf(w[v], sq[v], mb);
    float qf = 0.f;
    for (int u = 0; u < 32; ++u) {
        float tacc = 0.f;
        #pragma unroll
        for (int v = 0; v < 32; ++v) tacc = fmaf(qq[(u << 5) + v], w[v], tacc);
        qf = fmaf(w[u], tacc, qf);
    }
    atomicAdd(&ws[WS_YSUM + c], mb);
    atomicAdd(&ws[WS_YSQ + c], qf);
}

// ---------------------------------------------------------------------------
__global__ void finalize_kernel(const float* __restrict__ gamma,
                                const float* __restrict__ beta, float* ws) {
    const int c = threadIdx.x;  // 128
    const float invBN = 1.0f / 262144.0f;
    const float mean = ws[WS_YSUM + c] * invBN;
    const float var  = ws[WS_YSQ + c] * invBN - mean * mean;
    const float s = gamma[c] * rsqrtf(var + 1e-5f);
    ws[WS_SCALE + c] = s;
    ws[WS_BIAS + c]  = fmaf(-mean, s, beta[c]);
}

// ---------------------------------------------------------------------------
// Output: y[c,n] = scale_c * (w2b[c]·(inv*Q_n)) + bias_c.
// qsrc aliases out (Q lives in channels 0..31 stripes); each thread reads its
// 32 Q values before writing its 128 outputs -> per-thread ordering is safe,
// and no cross-block overlap (same b, same n-range only). NO __restrict__.
__global__ __launch_bounds__(256) void out_kernel(const float* qsrc, const float* ws,
                                                  float* out) {
    const int b = blockIdx.y;
    const int n = (blockIdx.x << 8) + threadIdx.x;
    const float* ksb = ws + WS_KS + (b << 5);
    const float* w2b = ws + WS_W2 + (b << 12);

    const float* qp = qsrc + (size_t)b * CC * NN + n;
    float qa[32];
    #pragma unroll
    for (int m = 0; m < 32; ++m) qa[m] = qp[(size_t)m * NN];

    float denom = 1e-6f;
    #pragma unroll
    for (int m = 0; m < 32; ++m) denom = fmaf(qa[m], ksb[m], denom);
    const float inv = 1.0f / (16384.0f * denom);
    #pragma unroll
    for (int m = 0; m < 32; ++m) qa[m] *= inv;

    float* op = out + (size_t)b * CC * NN + n;
    #pragma unroll 2
    for (int c = 0; c < CC; ++c) {
        const float4* w4 = (const float4*)(w2b + (c << 5));
        float t0 = 0.f, t1 = 0.f, t2 = 0.f, t3 = 0.f;
        #pragma unroll
        for (int q = 0; q < 8; ++q) {
            const float4 w = w4[q];
            t0 = fmaf(w.x, qa[4*q+0], t0);
            t1 = fmaf(w.y, qa[4*q+1], t1);
            t2 = fmaf(w.z, qa[4*q+2], t2);
            t3 = fmaf(w.w, qa[4*q+3], t3);
        }
        const float ysum = (t0 + t1) + (t2 + t3);
        op[(size_t)c * NN] = fmaf(ws[WS_SCALE + c], ysum, ws[WS_BIAS + c]);
    }
}

// ---------------------------------------------------------------------------
extern "C" void kernel_launch(void* const* d_in, const int* in_sizes, int n_in,
                              void* d_out, int out_size, void* d_ws, size_t ws_size,
                              hipStream_t stream) {
    const float* x     = (const float*)d_in[0];
    const float* Wq    = (const float*)d_in[1];
    const float* Wk    = (const float*)d_in[2];
    const float* Wv    = (const float*)d_in[3];
    const float* Wout  = (const float*)d_in[4];
    const float* gamma = (const float*)d_in[5];
    const float* beta  = (const float*)d_in[6];
    float* ws  = (float*)d_ws;
    float* out = (float*)d_out;

    // zero accumulators (KV, Ks, Sq, QQ, ysum, ysq) every launch
    hipMemsetAsync(ws, 0, (size_t)WS_ACCEND * sizeof(float), stream);

    wt_kernel<<<1, 128, 0, stream>>>(Wq, Wk, Wv, ws);
    proj_kernel<<<dim3(32, 16), 256, 0, stream>>>(x, ws, out);
    w2_kernel<<<16, 256, 0, stream>>>(Wout, ws);
    qq_kernel<<<dim3(16, 16), 256, 0, stream>>>(out, ws);
    bnstat_kernel<<<16, 128, 0, stream>>>(ws);
    finalize_kernel<<<1, 128, 0, stream>>>(gamma, beta, ws);
    out_kernel<<<dim3(64, 16), 256, 0, stream>>>(out, ws, out);
}

// Round 3
// 258.402 us; speedup vs baseline: 1.9477x; 1.2018x over previous
//
#include <hip/hip_runtime.h>

// Problem constants
#define BB 16
#define CC 128
#define MM 32
#define NN 16384   // H*W

// Workspace layout (float offsets)
#define WS_KV     0        // [16][32][32]
#define WS_KS     16384    // [16][32]
#define WS_SQ     16896    // [16][32]   sum_n Q'
#define WS_QQ     17408    // [16][32][32] sum_n Q'Q'^T
#define WS_YSUM   33792    // [128]
#define WS_YSQ    33920    // [128]
#define WS_ACCEND 34048    // zeroed region end
#define WS_SCALE  34048    // [128]
#define WS_BIAS   34176    // [128]
#define WS_W2     34304    // [16][128][32]
#define WS_WQT    99840    // [128][32]
#define WS_WKT    103936   // [128][32]
#define WS_WVT    108032   // [128][32]

__device__ __forceinline__ float phi_f(float z) {
    // elu(z) + 1 (alpha=1): z>0 -> z+1 ; z<=0 -> exp(z)
    return z > 0.f ? z + 1.f : __expf(z);
}

// ---------------------------------------------------------------------------
// Transpose projection weights [32][128] -> [128][32].
__global__ void wt_kernel(const float* __restrict__ Wq, const float* __restrict__ Wk,
                          const float* __restrict__ Wv, float* __restrict__ ws) {
    const int c = threadIdx.x;  // 128
    #pragma unroll
    for (int m = 0; m < MM; ++m) {
        ws[WS_WQT + c * MM + m] = Wq[m * CC + c];
        ws[WS_WKT + c * MM + m] = Wk[m * CC + c];
        ws[WS_WVT + c * MM + m] = Wv[m * CC + c];
    }
}

// ---------------------------------------------------------------------------
// Pass A: single read of x. k,v,q projections; store phi(q) to d_out stripes;
// accumulate KV[b], Ks[b].  grid (64,16) x 256; 256 pixels per block.
__global__ __launch_bounds__(256) void proj_kernel(const float* __restrict__ x,
                                                   float* ws, float* __restrict__ qout) {
    __shared__ __align__(16) float kt[256 * 36];
    __shared__ __align__(16) float vt[256 * 36];

    const float* wqT = ws + WS_WQT;
    const float* wkT = ws + WS_WKT;
    const float* wvT = ws + WS_WVT;

    const int b = blockIdx.y;
    const int t = threadIdx.x;
    const int l = t & 63;
    const int g = t >> 6;             // wave id
    const int m0 = (l >> 3) << 2;     // K-row group
    const int v0 = (l & 7) << 2;      // V-col group

    const int n = (blockIdx.x << 8) + t;

    float ka[32], va[32], qa[32];
    #pragma unroll
    for (int m = 0; m < 32; ++m) { ka[m] = 0.f; va[m] = 0.f; qa[m] = 0.f; }

    const float* xp = x + (size_t)b * CC * NN + n;
    #pragma unroll 4
    for (int c = 0; c < CC; ++c) {
        const float xv = xp[(size_t)c * NN];
        const float4* wk4 = (const float4*)(wkT + (c << 5));
        const float4* wv4 = (const float4*)(wvT + (c << 5));
        const float4* wq4 = (const float4*)(wqT + (c << 5));
        #pragma unroll
        for (int q = 0; q < 8; ++q) {
            const float4 wa = wk4[q];
            ka[4*q+0] = fmaf(wa.x, xv, ka[4*q+0]);
            ka[4*q+1] = fmaf(wa.y, xv, ka[4*q+1]);
            ka[4*q+2] = fmaf(wa.z, xv, ka[4*q+2]);
            ka[4*q+3] = fmaf(wa.w, xv, ka[4*q+3]);
            const float4 wb = wv4[q];
            va[4*q+0] = fmaf(wb.x, xv, va[4*q+0]);
            va[4*q+1] = fmaf(wb.y, xv, va[4*q+1]);
            va[4*q+2] = fmaf(wb.z, xv, va[4*q+2]);
            va[4*q+3] = fmaf(wb.w, xv, va[4*q+3]);
            const float4 wc = wq4[q];
            qa[4*q+0] = fmaf(wc.x, xv, qa[4*q+0]);
            qa[4*q+1] = fmaf(wc.y, xv, qa[4*q+1]);
            qa[4*q+2] = fmaf(wc.z, xv, qa[4*q+2]);
            qa[4*q+3] = fmaf(wc.w, xv, qa[4*q+3]);
        }
    }

    // store phi(Q) into d_out stripes (channels 0..31 of batch b)
    float* qp = qout + (size_t)b * CC * NN + n;
    #pragma unroll
    for (int m = 0; m < 32; ++m) qp[(size_t)m * NN] = phi_f(qa[m]);

    #pragma unroll
    for (int q = 0; q < 8; ++q) {
        float4 kk;
        kk.x = phi_f(ka[4*q+0]); kk.y = phi_f(ka[4*q+1]);
        kk.z = phi_f(ka[4*q+2]); kk.w = phi_f(ka[4*q+3]);
        *(float4*)&kt[t * 36 + 4*q] = kk;
        float4 vv;
        vv.x = va[4*q+0]; vv.y = va[4*q+1]; vv.z = va[4*q+2]; vv.w = va[4*q+3];
        *(float4*)&vt[t * 36 + 4*q] = vv;
    }
    __syncthreads();

    float kvacc[16];
    #pragma unroll
    for (int i = 0; i < 16; ++i) kvacc[i] = 0.f;
    float ksacc[4] = {0.f, 0.f, 0.f, 0.f};

    const int pbase = g << 6;
    for (int pp = 0; pp < 64; ++pp) {
        const int p = pbase + pp;
        const float4 kf = *(const float4*)&kt[p * 36 + m0];
        const float4 vf = *(const float4*)&vt[p * 36 + v0];
        kvacc[ 0] = fmaf(kf.x, vf.x, kvacc[ 0]);
        kvacc[ 1] = fmaf(kf.x, vf.y, kvacc[ 1]);
        kvacc[ 2] = fmaf(kf.x, vf.z, kvacc[ 2]);
        kvacc[ 3] = fmaf(kf.x, vf.w, kvacc[ 3]);
        kvacc[ 4] = fmaf(kf.y, vf.x, kvacc[ 4]);
        kvacc[ 5] = fmaf(kf.y, vf.y, kvacc[ 5]);
        kvacc[ 6] = fmaf(kf.y, vf.z, kvacc[ 6]);
        kvacc[ 7] = fmaf(kf.y, vf.w, kvacc[ 7]);
        kvacc[ 8] = fmaf(kf.z, vf.x, kvacc[ 8]);
        kvacc[ 9] = fmaf(kf.z, vf.y, kvacc[ 9]);
        kvacc[10] = fmaf(kf.z, vf.z, kvacc[10]);
        kvacc[11] = fmaf(kf.z, vf.w, kvacc[11]);
        kvacc[12] = fmaf(kf.w, vf.x, kvacc[12]);
        kvacc[13] = fmaf(kf.w, vf.y, kvacc[13]);
        kvacc[14] = fmaf(kf.w, vf.z, kvacc[14]);
        kvacc[15] = fmaf(kf.w, vf.w, kvacc[15]);
        if (v0 == 0) {
            ksacc[0] += kf.x; ksacc[1] += kf.y;
            ksacc[2] += kf.z; ksacc[3] += kf.w;
        }
    }

    // cross-wave LDS reduction, then one atomic per entry per block
    __syncthreads();
    #pragma unroll
    for (int i = 0; i < 16; ++i) kt[t * 17 + i] = kvacc[i];
    if (v0 == 0) {
        const int r = l >> 3;
        #pragma unroll
        for (int i = 0; i < 4; ++i) vt[(g * 8 + r) * 4 + i] = ksacc[i];
    }
    __syncthreads();
    if (t < 64) {
        float* kvb = ws + WS_KV + (b << 10);
        #pragma unroll
        for (int i = 0; i < 16; ++i) {
            const float s = kt[t*17+i] + kt[(t+64)*17+i] + kt[(t+128)*17+i] + kt[(t+192)*17+i];
            atomicAdd(&kvb[(m0 + (i >> 2)) * 32 + v0 + (i & 3)], s);
        }
    }
    if (t < 8) {
        #pragma unroll
        for (int i = 0; i < 4; ++i) {
            const float s = vt[t*4+i] + vt[(8+t)*4+i] + vt[(16+t)*4+i] + vt[(24+t)*4+i];
            atomicAdd(&ws[WS_KS + (b << 5) + t * 4 + i], s);
        }
    }
}

// ---------------------------------------------------------------------------
// W2[b] = Wout (128x32) @ KV[b] (32x32)
__global__ __launch_bounds__(256) void w2_kernel(const float* __restrict__ Wout,
                                                 float* ws) {
    const int b = blockIdx.x;
    const float* kvb = ws + WS_KV + (b << 10);
    float* w2b = ws + WS_W2 + (b << 12);
    const int t = threadIdx.x;
    #pragma unroll
    for (int i = 0; i < 16; ++i) {
        const int o = (i << 8) + t;
        const int c = o >> 5, v = o & 31;
        float acc = 0.f;
        #pragma unroll
        for (int m = 0; m < 32; ++m)
            acc = fmaf(Wout[(c << 5) + m], kvb[(m << 5) + v], acc);
        w2b[o] = acc;
    }
}

// ---------------------------------------------------------------------------
// Pass C: read phi(Q), fold inv; accumulate Sq[b], QQ[b].
// grid (32,16) x 256, 2 tiles of 256.
__global__ __launch_bounds__(256) void qq_kernel(const float* qsrc, float* ws) {
    __shared__ __align__(16) float qt[256 * 36];

    const int b = blockIdx.y;
    const int t = threadIdx.x;
    const int l = t & 63;
    const int g = t >> 6;
    const int m0 = (l >> 3) << 2;
    const int v0 = (l & 7) << 2;

    float qqacc[16];
    #pragma unroll
    for (int i = 0; i < 16; ++i) qqacc[i] = 0.f;
    float sqacc[4] = {0.f, 0.f, 0.f, 0.f};

    const float* ksb = ws + WS_KS + (b << 5);

    for (int tile = 0; tile < 2; ++tile) {
        const int n = (blockIdx.x << 9) + (tile << 8) + t;
        const float* qp = qsrc + (size_t)b * CC * NN + n;
        float qa[32];
        #pragma unroll
        for (int m = 0; m < 32; ++m) qa[m] = qp[(size_t)m * NN];

        float denom = 1e-6f;
        #pragma unroll
        for (int m = 0; m < 32; ++m) denom = fmaf(qa[m], ksb[m], denom);
        const float inv = 1.0f / (16384.0f * denom);
        #pragma unroll
        for (int m = 0; m < 32; ++m) qa[m] *= inv;

        __syncthreads();
        #pragma unroll
        for (int q = 0; q < 8; ++q)
            *(float4*)&qt[t * 36 + 4*q] = *(float4*)&qa[4*q];
        __syncthreads();

        const int pbase = g << 6;
        for (int pp = 0; pp < 64; ++pp) {
            const int p = pbase + pp;
            const float4 uf = *(const float4*)&qt[p * 36 + m0];
            const float4 vf = *(const float4*)&qt[p * 36 + v0];
            qqacc[ 0] = fmaf(uf.x, vf.x, qqacc[ 0]);
            qqacc[ 1] = fmaf(uf.x, vf.y, qqacc[ 1]);
            qqacc[ 2] = fmaf(uf.x, vf.z, qqacc[ 2]);
            qqacc[ 3] = fmaf(uf.x, vf.w, qqacc[ 3]);
            qqacc[ 4] = fmaf(uf.y, vf.x, qqacc[ 4]);
            qqacc[ 5] = fmaf(uf.y, vf.y, qqacc[ 5]);
            qqacc[ 6] = fmaf(uf.y, vf.z, qqacc[ 6]);
            qqacc[ 7] = fmaf(uf.y, vf.w, qqacc[ 7]);
            qqacc[ 8] = fmaf(uf.z, vf.x, qqacc[ 8]);
            qqacc[ 9] = fmaf(uf.z, vf.y, qqacc[ 9]);
            qqacc[10] = fmaf(uf.z, vf.z, qqacc[10]);
            qqacc[11] = fmaf(uf.z, vf.w, qqacc[11]);
            qqacc[12] = fmaf(uf.w, vf.x, qqacc[12]);
            qqacc[13] = fmaf(uf.w, vf.y, qqacc[13]);
            qqacc[14] = fmaf(uf.w, vf.z, qqacc[14]);
            qqacc[15] = fmaf(uf.w, vf.w, qqacc[15]);
            if (v0 == 0) {
                sqacc[0] += uf.x; sqacc[1] += uf.y;
                sqacc[2] += uf.z; sqacc[3] += uf.w;
            }
        }
    }

    __syncthreads();
    #pragma unroll
    for (int i = 0; i < 16; ++i) qt[t * 17 + i] = qqacc[i];
    if (v0 == 0) {
        const int r = l >> 3;
        #pragma unroll
        for (int i = 0; i < 4; ++i) qt[4352 + (g * 8 + r) * 4 + i] = sqacc[i];
    }
    __syncthreads();
    if (t < 64) {
        float* qqb = ws + WS_QQ + (b << 10);
        #pragma unroll
        for (int i = 0; i < 16; ++i) {
            const float s = qt[t*17+i] + qt[(t+64)*17+i] + qt[(t+128)*17+i] + qt[(t+192)*17+i];
            atomicAdd(&qqb[(m0 + (i >> 2)) * 32 + v0 + (i & 3)], s);
        }
    }
    if (t < 8) {
        #pragma unroll
        for (int i = 0; i < 4; ++i) {
            const float s = qt[4352 + t*4+i] + qt[4352 + (8+t)*4+i]
                          + qt[4352 + (16+t)*4+i] + qt[4352 + (24+t)*4+i];
            atomicAdd(&ws[WS_SQ + (b << 5) + t * 4 + i], s);
        }
    }
}

// ---------------------------------------------------------------------------
// BN stats from moments: ysum_c += w2b[c]·Sq_b ; ysq_c += w2b[c]·QQ_b·w2b[c]^T
__global__ __launch_bounds__(128) void bnstat_kernel(float* ws) {
    const int b = blockIdx.x;   // 16
    const int c = threadIdx.x;  // 128
    const float* w2c = ws + WS_W2 + (b << 12) + (c << 5);
    const float* sq  = ws + WS_SQ + (b << 5);
    const float* qq  = ws + WS_QQ + (b << 10);
    float w[32];
    #pragma unroll
    for (int v = 0; v < 32; ++v) w[v] = w2c[v];
    float mb = 0.f;
    #pragma unroll
    for (int v = 0; v < 32; ++v) mb = fmaf(w[v], sq[v], mb);
    float qf = 0.f;
    for (int u = 0; u < 32; ++u) {
        float tacc = 0.f;
        #pragma unroll
        for (int v = 0; v < 32; ++v) tacc = fmaf(qq[(u << 5) + v], w[v], tacc);
        qf = fmaf(w[u], tacc, qf);
    }
    atomicAdd(&ws[WS_YSUM + c], mb);
    atomicAdd(&ws[WS_YSQ + c], qf);
}

// ---------------------------------------------------------------------------
__global__ void finalize_kernel(const float* __restrict__ gamma,
                                const float* __restrict__ beta, float* ws) {
    const int c = threadIdx.x;  // 128
    const float invBN = 1.0f / 262144.0f;
    const float mean = ws[WS_YSUM + c] * invBN;
    const float var  = ws[WS_YSQ + c] * invBN - mean * mean;
    const float s = gamma[c] * rsqrtf(var + 1e-5f);
    ws[WS_SCALE + c] = s;
    ws[WS_BIAS + c]  = fmaf(-mean, s, beta[c]);
}

// ---------------------------------------------------------------------------
// Output: y[c,n] = scale_c * (w2b[c]·(inv*Q_n)) + bias_c, 2 pixels/thread.
// w2/scale/bias staged in LDS once -> no global loads in the store loop.
// qsrc aliases out: each thread reads its 32 Q values (its own 2 pixels)
// BEFORE any store; blocks touch disjoint (b, n) ranges -> safe.
__global__ __launch_bounds__(256) void out_kernel(const float* qsrc, const float* ws,
                                                  float* out) {
    __shared__ __align__(16) float w2s[CC * MM];   // 16 KB
    __shared__ float scs[CC];
    __shared__ float bis[CC];

    const int b = blockIdx.y;
    const int t = threadIdx.x;

    // stage w2[b], scale, bias into LDS
    const float* w2b = ws + WS_W2 + (b << 12);
    #pragma unroll
    for (int i = 0; i < 4; ++i) {
        const int idx = (i << 8) + t;                       // float4 index
        *(float4*)&w2s[idx << 2] = *(const float4*)&w2b[idx << 2];
    }
    if (t < CC) {
        scs[t] = ws[WS_SCALE + t];
        bis[t] = ws[WS_BIAS + t];
    }

    const int n0 = (blockIdx.x << 9) + (t << 1);
    const float* ksb = ws + WS_KS + (b << 5);

    // load Q for this thread's 2 pixels (before any stores!)
    const float* qp = qsrc + (size_t)b * CC * NN + n0;
    float qa[32], qb[32];
    #pragma unroll
    for (int m = 0; m < 32; ++m) {
        const float2 v = *(const float2*)&qp[(size_t)m * NN];
        qa[m] = v.x; qb[m] = v.y;
    }
    float d0 = 1e-6f, d1 = 1e-6f;
    #pragma unroll
    for (int m = 0; m < 32; ++m) {
        const float k = ksb[m];
        d0 = fmaf(qa[m], k, d0);
        d1 = fmaf(qb[m], k, d1);
    }
    const float i0 = 1.0f / (16384.0f * d0);
    const float i1 = 1.0f / (16384.0f * d1);
    #pragma unroll
    for (int m = 0; m < 32; ++m) { qa[m] *= i0; qb[m] *= i1; }

    __syncthreads();

    float* op = out + (size_t)b * CC * NN + n0;
    #pragma unroll 4
    for (int c = 0; c < CC; ++c) {
        const float* wr = &w2s[c << 5];
        float a0 = 0.f, a1 = 0.f, a2 = 0.f, a3 = 0.f;
        float b0 = 0.f, b1 = 0.f, b2 = 0.f, b3 = 0.f;
        #pragma unroll
        for (int q = 0; q < 8; ++q) {
            const float4 w = *(const float4*)&wr[q << 2];
            a0 = fmaf(w.x, qa[4*q+0], a0);
            a1 = fmaf(w.y, qa[4*q+1], a1);
            a2 = fmaf(w.z, qa[4*q+2], a2);
            a3 = fmaf(w.w, qa[4*q+3], a3);
            b0 = fmaf(w.x, qb[4*q+0], b0);
            b1 = fmaf(w.y, qb[4*q+1], b1);
            b2 = fmaf(w.z, qb[4*q+2], b2);
            b3 = fmaf(w.w, qb[4*q+3], b3);
        }
        const float s = scs[c], bi = bis[c];
        float2 r;
        r.x = fmaf(s, (a0 + a1) + (a2 + a3), bi);
        r.y = fmaf(s, (b0 + b1) + (b2 + b3), bi);
        *(float2*)&op[(size_t)c * NN] = r;
    }
}

// ---------------------------------------------------------------------------
extern "C" void kernel_launch(void* const* d_in, const int* in_sizes, int n_in,
                              void* d_out, int out_size, void* d_ws, size_t ws_size,
                              hipStream_t stream) {
    const float* x     = (const float*)d_in[0];
    const float* Wq    = (const float*)d_in[1];
    const float* Wk    = (const float*)d_in[2];
    const float* Wv    = (const float*)d_in[3];
    const float* Wout  = (const float*)d_in[4];
    const float* gamma = (const float*)d_in[5];
    const float* beta  = (const float*)d_in[6];
    float* ws  = (float*)d_ws;
    float* out = (float*)d_out;

    // zero accumulators (KV, Ks, Sq, QQ, ysum, ysq) every launch
    hipMemsetAsync(ws, 0, (size_t)WS_ACCEND * sizeof(float), stream);

    wt_kernel<<<1, 128, 0, stream>>>(Wq, Wk, Wv, ws);
    proj_kernel<<<dim3(64, 16), 256, 0, stream>>>(x, ws, out);
    w2_kernel<<<16, 256, 0, stream>>>(Wout, ws);
    qq_kernel<<<dim3(32, 16), 256, 0, stream>>>(out, ws);
    bnstat_kernel<<<16, 128, 0, stream>>>(ws);
    finalize_kernel<<<1, 128, 0, stream>>>(gamma, beta, ws);
    out_kernel<<<dim3(32, 16), 256, 0, stream>>>(out, ws, out);
}